// Round 1
// baseline (425.457 us; speedup 1.0000x reference)
//
#include <hip/hip_runtime.h>

// Problem constants (match reference setup_inputs)
#define NSAMP 65536
#define DDIM  128

// One wave (64 lanes) per sample; lane l owns elements {2l, 2l+1} as float2.
// Projection is linear in x, so project (h + r - t) once instead of 3 times.
__global__ __launch_bounds__(256) void transh_kernel(
    const int* __restrict__ pos_h, const int* __restrict__ pos_t, const int* __restrict__ pos_r,
    const int* __restrict__ neg_h, const int* __restrict__ neg_t, const int* __restrict__ neg_r,
    const float* __restrict__ ent, const float* __restrict__ vvrel, const float* __restrict__ bases,
    float* __restrict__ out)
{
    const int gtid = blockIdx.x * blockDim.x + threadIdx.x;
    const int samp = gtid >> 6;           // wave index == sample index
    const int lane = threadIdx.x & 63;
    if (samp >= NSAMP) return;

    // Wave-uniform index loads (compiler emits s_load via readfirstlane path)
    const int ph_i = pos_h[samp];
    const int pt_i = pos_t[samp];
    const int pr_i = pos_r[samp];
    const int nh_i = neg_h[samp];
    const int nt_i = neg_t[samp];
    const int nr_i = neg_r[samp];

    const float2* v2   = (const float2*)(bases + (size_t)pr_i * DDIM);
    const float2* ph2  = (const float2*)(ent   + (size_t)ph_i * DDIM);
    const float2* pt2  = (const float2*)(ent   + (size_t)pt_i * DDIM);
    const float2* prv2 = (const float2*)(vvrel + (size_t)pr_i * DDIM);
    const float2* nh2  = (const float2*)(ent   + (size_t)nh_i * DDIM);
    const float2* nt2  = (const float2*)(ent   + (size_t)nt_i * DDIM);
    const float2* nrv2 = (const float2*)(vvrel + (size_t)nr_i * DDIM);

    const float2 v  = v2[lane];
    const float2 a  = ph2[lane];
    const float2 c  = pt2[lane];
    const float2 b  = prv2[lane];
    const float2 na = nh2[lane];
    const float2 nc = nt2[lane];
    const float2 nb = nrv2[lane];

    float2 sp, sn;
    sp.x = a.x + b.x - c.x;
    sp.y = a.y + b.y - c.y;
    sn.x = na.x + nb.x - nc.x;
    sn.y = na.y + nb.y - nc.y;

    float vv  = v.x * v.x + v.y * v.y;
    float vsp = v.x * sp.x + v.y * sp.y;
    float vsn = v.x * sn.x + v.y * sn.y;

    // 64-lane butterfly reduction of 3 values
    #pragma unroll
    for (int off = 32; off > 0; off >>= 1) {
        vv  += __shfl_xor(vv,  off, 64);
        vsp += __shfl_xor(vsp, off, 64);
        vsn += __shfl_xor(vsn, off, 64);
    }

    const float cp = vsp / vv;
    const float cn = vsn / vv;

    float ap = fabsf(sp.x - cp * v.x) + fabsf(sp.y - cp * v.y);
    float an = fabsf(sn.x - cn * v.x) + fabsf(sn.y - cn * v.y);

    #pragma unroll
    for (int off = 32; off > 0; off >>= 1) {
        ap += __shfl_xor(ap, off, 64);
        an += __shfl_xor(an, off, 64);
    }

    if (lane == 0) {
        out[samp]         = ap;  // pos score
        out[NSAMP + samp] = an;  // neg score
    }
}

extern "C" void kernel_launch(void* const* d_in, const int* in_sizes, int n_in,
                              void* d_out, int out_size, void* d_ws, size_t ws_size,
                              hipStream_t stream) {
    const int*   pos_h = (const int*)d_in[0];
    const int*   pos_t = (const int*)d_in[1];
    const int*   pos_r = (const int*)d_in[2];
    const int*   neg_h = (const int*)d_in[3];
    const int*   neg_t = (const int*)d_in[4];
    const int*   neg_r = (const int*)d_in[5];
    const float* ent   = (const float*)d_in[6];
    const float* vvrel = (const float*)d_in[7];
    const float* bases = (const float*)d_in[8];
    float* out = (float*)d_out;

    // 1 wave per sample, 4 waves per block
    const int threads = 256;
    const int blocks  = (NSAMP * 64) / threads;  // 16384
    transh_kernel<<<blocks, threads, 0, stream>>>(
        pos_h, pos_t, pos_r, neg_h, neg_t, neg_r, ent, vvrel, bases, out);
}

// Round 2
// 419.427 us; speedup vs baseline: 1.0144x; 1.0144x over previous
//
#include <hip/hip_runtime.h>

// Problem constants (match reference setup_inputs)
#define NSAMP 65536
#define DDIM  128

// Half-wave (32 lanes) per sample; lane l owns elements {4l..4l+3} as float4.
// A full wave covers 2 samples, so each row-gather instruction moves
// 64 lanes x 16 B = 1 KiB (the coalescing sweet spot).
// Projection is linear in x, so project (h + r - t) once per score.
__global__ __launch_bounds__(256) void transh_kernel(
    const int* __restrict__ pos_h, const int* __restrict__ pos_t, const int* __restrict__ pos_r,
    const int* __restrict__ neg_h, const int* __restrict__ neg_t, const int* __restrict__ neg_r,
    const float* __restrict__ ent, const float* __restrict__ vvrel, const float* __restrict__ bases,
    float* __restrict__ out)
{
    const int tid  = blockIdx.x * blockDim.x + threadIdx.x;
    const int samp = tid >> 5;            // half-wave index == sample index
    const int sub  = threadIdx.x & 31;    // lane within the 32-lane group
    if (samp >= NSAMP) return;

    const int ph_i = pos_h[samp];
    const int pt_i = pos_t[samp];
    const int pr_i = pos_r[samp];
    const int nh_i = neg_h[samp];
    const int nt_i = neg_t[samp];
    const int nr_i = neg_r[samp];

    const float4* v4   = (const float4*)(bases + (size_t)pr_i * DDIM);
    const float4* ph4  = (const float4*)(ent   + (size_t)ph_i * DDIM);
    const float4* pt4  = (const float4*)(ent   + (size_t)pt_i * DDIM);
    const float4* prv4 = (const float4*)(vvrel + (size_t)pr_i * DDIM);
    const float4* nh4  = (const float4*)(ent   + (size_t)nh_i * DDIM);
    const float4* nt4  = (const float4*)(ent   + (size_t)nt_i * DDIM);
    const float4* nrv4 = (const float4*)(vvrel + (size_t)nr_i * DDIM);

    const float4 v  = v4[sub];
    const float4 a  = ph4[sub];
    const float4 c  = pt4[sub];
    const float4 b  = prv4[sub];
    const float4 na = nh4[sub];
    const float4 nc = nt4[sub];
    const float4 nb = nrv4[sub];

    float4 sp, sn;
    sp.x = a.x + b.x - c.x;  sp.y = a.y + b.y - c.y;
    sp.z = a.z + b.z - c.z;  sp.w = a.w + b.w - c.w;
    sn.x = na.x + nb.x - nc.x;  sn.y = na.y + nb.y - nc.y;
    sn.z = na.z + nb.z - nc.z;  sn.w = na.w + nb.w - nc.w;

    float vv  = v.x * v.x + v.y * v.y + v.z * v.z + v.w * v.w;
    float vsp = v.x * sp.x + v.y * sp.y + v.z * sp.z + v.w * sp.w;
    float vsn = v.x * sn.x + v.y * sn.y + v.z * sn.z + v.w * sn.w;

    // 32-lane butterfly (xor offsets <=16 stay within the half-wave)
    #pragma unroll
    for (int off = 16; off > 0; off >>= 1) {
        vv  += __shfl_xor(vv,  off, 64);
        vsp += __shfl_xor(vsp, off, 64);
        vsn += __shfl_xor(vsn, off, 64);
    }

    const float cp = vsp / vv;
    const float cn = vsn / vv;

    float ap = fabsf(sp.x - cp * v.x) + fabsf(sp.y - cp * v.y)
             + fabsf(sp.z - cp * v.z) + fabsf(sp.w - cp * v.w);
    float an = fabsf(sn.x - cn * v.x) + fabsf(sn.y - cn * v.y)
             + fabsf(sn.z - cn * v.z) + fabsf(sn.w - cn * v.w);

    #pragma unroll
    for (int off = 16; off > 0; off >>= 1) {
        ap += __shfl_xor(ap, off, 64);
        an += __shfl_xor(an, off, 64);
    }

    if (sub == 0) {
        out[samp]         = ap;  // pos score
        out[NSAMP + samp] = an;  // neg score
    }
}

extern "C" void kernel_launch(void* const* d_in, const int* in_sizes, int n_in,
                              void* d_out, int out_size, void* d_ws, size_t ws_size,
                              hipStream_t stream) {
    const int*   pos_h = (const int*)d_in[0];
    const int*   pos_t = (const int*)d_in[1];
    const int*   pos_r = (const int*)d_in[2];
    const int*   neg_h = (const int*)d_in[3];
    const int*   neg_t = (const int*)d_in[4];
    const int*   neg_r = (const int*)d_in[5];
    const float* ent   = (const float*)d_in[6];
    const float* vvrel = (const float*)d_in[7];
    const float* bases = (const float*)d_in[8];
    float* out = (float*)d_out;

    // Half-wave per sample: 8 samples per 256-thread block
    const int threads = 256;
    const int blocks  = (NSAMP * 32) / threads;  // 8192
    transh_kernel<<<blocks, threads, 0, stream>>>(
        pos_h, pos_t, pos_r, neg_h, neg_t, neg_r, ent, vvrel, bases, out);
}